// Round 7
// baseline (87.924 us; speedup 1.0000x reference)
//
#include <hip/hip_runtime.h>
#include <hip/hip_bf16.h>

typedef unsigned short u16;
typedef __attribute__((ext_vector_type(8))) short short8;
typedef __attribute__((ext_vector_type(4))) float f32x4;

#define BSZ   4096
#define INF   1024
#define FEAT  512
#define NCLS  1000
#define NPAD  1024
#define DTOT  2048

__device__ __forceinline__ u16 f2bf(float f) {
  unsigned int x = __float_as_uint(f);
  x += 0x7fffu + ((x >> 16) & 1u);   // RNE; inputs finite, no NaN path needed
  return (u16)(x >> 16);
}
__device__ __forceinline__ float bf2f(u16 h) {
  return __uint_as_float((unsigned int)h << 16);
}
__device__ __forceinline__ void gload_lds16(const void* g, void* l) {
  __builtin_amdgcn_global_load_lds(
      (const __attribute__((address_space(1))) void*)g,
      (__attribute__((address_space(3))) void*)l, 16, 0, 0);
}

// -------- fp32 -> bf16 convert, 4 source tensors in one dispatch -----------
__global__ __launch_bounds__(256) void cvt_bf16_x4(const float* __restrict__ x0,
                                                   const float* __restrict__ x1,
                                                   const float* __restrict__ x2,
                                                   const float* __restrict__ x3,
                                                   u16* __restrict__ outp, int n8) {
  int i = blockIdx.x * 256 + threadIdx.x;
  if (i >= n8) return;
  const float* in = (blockIdx.y & 2) ? ((blockIdx.y & 1) ? x3 : x2)
                                     : ((blockIdx.y & 1) ? x1 : x0);
  const float4* p = (const float4*)in;
  float4 a = p[2 * i], b = p[2 * i + 1];
  short8 o;
  o[0] = (short)f2bf(a.x); o[1] = (short)f2bf(a.y);
  o[2] = (short)f2bf(a.z); o[3] = (short)f2bf(a.w);
  o[4] = (short)f2bf(b.x); o[5] = (short)f2bf(b.y);
  o[6] = (short)f2bf(b.z); o[7] = (short)f2bf(b.w);
  *(short8*)&outp[(size_t)blockIdx.y * n8 * 8 + (size_t)i * 8] = o;
}

__global__ __launch_bounds__(256) void cvt_bf16(const float* __restrict__ in,
                                                u16* __restrict__ outp, int n8) {
  int i = blockIdx.x * 256 + threadIdx.x;
  if (i >= n8) return;
  const float4* p = (const float4*)in;
  float4 a = p[2 * i], b = p[2 * i + 1];
  short8 o;
  o[0] = (short)f2bf(a.x); o[1] = (short)f2bf(a.y);
  o[2] = (short)f2bf(a.z); o[3] = (short)f2bf(a.w);
  o[4] = (short)f2bf(b.x); o[5] = (short)f2bf(b.y);
  o[6] = (short)f2bf(b.z); o[7] = (short)f2bf(b.w);
  *(short8*)&outp[(size_t)i * 8] = o;
}

// ------------- centers: convert to bf16 (padded to 1024 rows) + c2 ---------
__global__ __launch_bounds__(256) void cvt_centers(const float* __restrict__ cen,
                                                   u16* __restrict__ Cb,
                                                   float* __restrict__ c2) {
  const int row = blockIdx.x;   // 0..1023
  const int t = threadIdx.x;    // 256 threads, 8 elems each (D=2048)
  float s = 0.f;
  if (row < NCLS) {
    const float4* p = (const float4*)(cen + (size_t)row * DTOT) + 2 * t;
    float4 a = p[0], b = p[1];
    short8 o;
    o[0] = (short)f2bf(a.x); o[1] = (short)f2bf(a.y);
    o[2] = (short)f2bf(a.z); o[3] = (short)f2bf(a.w);
    o[4] = (short)f2bf(b.x); o[5] = (short)f2bf(b.y);
    o[6] = (short)f2bf(b.z); o[7] = (short)f2bf(b.w);
    *(short8*)&Cb[(size_t)row * DTOT + t * 8] = o;
    s = a.x * a.x + a.y * a.y + a.z * a.z + a.w * a.w +
        b.x * b.x + b.y * b.y + b.z * b.z + b.w * b.w;
  } else {
    short8 z = {0, 0, 0, 0, 0, 0, 0, 0};
    *(short8*)&Cb[(size_t)row * DTOT + t * 8] = z;
  }
#pragma unroll
  for (int o = 32; o > 0; o >>= 1) s += __shfl_xor(s, o);
  __shared__ float red[4];
  if ((t & 63) == 0) red[t >> 6] = s;
  __syncthreads();
  if (t == 0) c2[row] = red[0] + red[1] + red[2] + red[3];
}

// ---------------- per-row sum of squares over bf16 feat --------------------
__global__ __launch_bounds__(256) void row_sumsq(const u16* __restrict__ X,
                                                 float* __restrict__ f2) {
  const int row = blockIdx.x;
  const int t = threadIdx.x;
  short8 v = *(const short8*)&X[(size_t)row * DTOT + t * 8];
  float s = 0.f;
#pragma unroll
  for (int q = 0; q < 8; ++q) { float f = bf2f((u16)v[q]); s += f * f; }
#pragma unroll
  for (int o = 32; o > 0; o >>= 1) s += __shfl_xor(s, o);
  __shared__ float red[4];
  if ((t & 63) == 0) red[t >> 6] = s;
  __syncthreads();
  if (t == 0) f2[row] = red[0] + red[1] + red[2] + red[3];
}

// ---------------- feature GEMM: feat = relu(X @ W^T + b), bf16 -------------
// 128x128 tile, 4 waves (2x2, wave 64x64), dbuf 2-barrier loop, XOR
// slot-swizzle, XCD-chunked, grid 512 = 2 blocks/CU. Plain epilogue
// (bias+relu+store ONLY -- the fused f2p shfl-reduce epilogue measured
// +25us across R4-R6; f2 is a separate 3.5us memory pass instead).
__global__ __launch_bounds__(256) void feat_gemm(const u16* __restrict__ Xb,
                                                 const u16* __restrict__ Wb,
                                                 const float* __restrict__ bf_,
                                                 const float* __restrict__ br_,
                                                 u16* __restrict__ Fb) {
  __shared__ u16 As[2][128 * 64];
  __shared__ u16 Bs[2][128 * 64];
  const int t = threadIdx.x;
  const int lane = t & 63;
  const int wid = t >> 6;
  const int wr = (wid >> 1) * 64;
  const int wc = (wid & 1) * 64;
  // XCD-chunked swizzle: 512 wgs -> 64 consecutive per XCD
  const int lid = blockIdx.x;
  const int swg = (lid & 7) * 64 + (lid >> 3);
  const int bm0 = (swg >> 4) * 128;      // M block
  const int n  = swg & 15;               // N block 0..15
  const int gc0 = n * 128;               // global feat col
  const int g = n >> 2;                  // quadrant 0..3
  const int bn0 = (n & 3) * 128;         // col within W
  const u16* A = Xb + (size_t)g * BSZ * INF;
  const u16* Bt = Wb + (g ? (size_t)FEAT * INF : 0);
  const float* bias = g ? br_ : bf_;

  const int r8 = t >> 3;                          // staging row 0..31 (+32/it)
  const int kcs = (((t & 7) ^ (r8 & 7)) << 3);    // swizzled source slot
  const int l15 = lane & 15;
  const int l4 = lane >> 4;
  const int swz = l15 & 7;

  f32x4 acc[4][4] = {};

  auto stage = [&](int buf, int k0) {
#pragma unroll
    for (int it = 0; it < 4; ++it) {
      gload_lds16(&A[(size_t)(bm0 + it * 32 + r8) * INF + k0 + kcs],
                  &As[buf][(it * 256 + (wid << 6)) * 8]);
      gload_lds16(&Bt[(size_t)(bn0 + it * 32 + r8) * INF + k0 + kcs],
                  &Bs[buf][(it * 256 + (wid << 6)) * 8]);
    }
  };
  auto comp = [&](int buf) {
#pragma unroll
    for (int ks = 0; ks < 2; ++ks) {
      const int so = (((ks * 4 + l4) ^ swz) << 3);
      short8 av[4], bv[4];
#pragma unroll
      for (int i = 0; i < 4; ++i)
        av[i] = *(const short8*)&As[buf][(wr + i * 16 + l15) * 64 + so];
#pragma unroll
      for (int j = 0; j < 4; ++j)
        bv[j] = *(const short8*)&Bs[buf][(wc + j * 16 + l15) * 64 + so];
#pragma unroll
      for (int i = 0; i < 4; ++i)
#pragma unroll
        for (int j = 0; j < 4; ++j)
          acc[i][j] = __builtin_amdgcn_mfma_f32_16x16x32_bf16(av[i], bv[j],
                                                              acc[i][j], 0, 0, 0);
    }
  };

  stage(0, 0);
  __syncthreads();
  for (int k0 = 0; k0 < INF; k0 += 128) {
    stage(1, k0 + 64);
    comp(0);
    __syncthreads();
    if (k0 + 128 < INF) stage(0, k0 + 128);
    comp(1);
    __syncthreads();
  }

#pragma unroll
  for (int j = 0; j < 4; ++j) {
    const int col = gc0 + wc + j * 16 + l15;
    const float bval = bias[bn0 + wc + j * 16 + l15];
#pragma unroll
    for (int i = 0; i < 4; ++i) {
#pragma unroll
      for (int r = 0; r < 4; ++r) {
        const int row = bm0 + wr + i * 16 + l4 * 4 + r;
        float v = fmaxf(acc[i][j][r] + bval, 0.f);
        Fb[(size_t)row * DTOT + col] = f2bf(v);
      }
    }
  }
}

// ---- distance GEMM split-K: P[k] = feat[:, k*1024:(k+1)*1024] @ Cb^T ------
// 128x128 tile, dbuf, grid 32m x 8n x 2k = 512 blocks = 2/CU.
__global__ __launch_bounds__(256) void dist_gemm_sk(const u16* __restrict__ Fb,
                                                    const u16* __restrict__ Cb,
                                                    float* __restrict__ P) {
  __shared__ u16 As[2][128 * 64];
  __shared__ u16 Bs[2][128 * 64];
  const int t = threadIdx.x;
  const int lane = t & 63;
  const int wid = t >> 6;
  const int wr = (wid >> 1) * 64;
  const int wc = (wid & 1) * 64;
  const int lid = blockIdx.x;
  const int swg = (lid & 7) * 64 + (lid >> 3);
  const int n = swg & 7;                 // 0..7
  const int kidx = (swg >> 3) & 1;       // K split 0..1
  const int bm0 = (swg >> 4) * 128;      // 0..31 -> rows
  const int bn0 = n * 128;               // padded class col
  const int kbase = kidx * 1024;

  const int r8 = t >> 3;
  const int kcs = (((t & 7) ^ (r8 & 7)) << 3);
  const int l15 = lane & 15;
  const int l4 = lane >> 4;
  const int swz = l15 & 7;

  f32x4 acc[4][4] = {};

  auto stage = [&](int buf, int k0) {
#pragma unroll
    for (int it = 0; it < 4; ++it) {
      gload_lds16(&Fb[(size_t)(bm0 + it * 32 + r8) * DTOT + k0 + kcs],
                  &As[buf][(it * 256 + (wid << 6)) * 8]);
      gload_lds16(&Cb[(size_t)(bn0 + it * 32 + r8) * DTOT + k0 + kcs],
                  &Bs[buf][(it * 256 + (wid << 6)) * 8]);
    }
  };
  auto comp = [&](int buf) {
#pragma unroll
    for (int ks = 0; ks < 2; ++ks) {
      const int so = (((ks * 4 + l4) ^ swz) << 3);
      short8 av[4], bv[4];
#pragma unroll
      for (int i = 0; i < 4; ++i)
        av[i] = *(const short8*)&As[buf][(wr + i * 16 + l15) * 64 + so];
#pragma unroll
      for (int j = 0; j < 4; ++j)
        bv[j] = *(const short8*)&Bs[buf][(wc + j * 16 + l15) * 64 + so];
#pragma unroll
      for (int i = 0; i < 4; ++i)
#pragma unroll
        for (int j = 0; j < 4; ++j)
          acc[i][j] = __builtin_amdgcn_mfma_f32_16x16x32_bf16(av[i], bv[j],
                                                              acc[i][j], 0, 0, 0);
    }
  };

  stage(0, kbase);
  __syncthreads();
  for (int k0 = kbase; k0 < kbase + 1024; k0 += 128) {
    stage(1, k0 + 64);
    comp(0);
    __syncthreads();
    if (k0 + 128 < kbase + 1024) stage(0, k0 + 128);
    comp(1);
    __syncthreads();
  }

  float* Pk = P + (size_t)kidx * BSZ * NPAD;
#pragma unroll
  for (int j = 0; j < 4; ++j) {
    const int col = bn0 + wc + j * 16 + l15;
#pragma unroll
    for (int i = 0; i < 4; ++i) {
#pragma unroll
      for (int r = 0; r < 4; ++r) {
        const int row = bm0 + wr + i * 16 + l4 * 4 + r;
        Pk[(size_t)row * NPAD + col] = acc[i][j][r];
      }
    }
  }
}

// ------ combine: out = -0.1*sqrt(max(f2 + c2 - 2*(P0+P1), 0)) --------------
__global__ __launch_bounds__(256) void combine(const float* __restrict__ P,
                                               const float* __restrict__ f2,
                                               const float* __restrict__ c2,
                                               float* __restrict__ out) {
  const int row = blockIdx.x;
  const int c = threadIdx.x * 4;
  if (c >= NCLS) return;
  const float4 p0 = *(const float4*)&P[(size_t)row * NPAD + c];
  const float4 p1 = *(const float4*)&P[(size_t)(BSZ + row) * NPAD + c];
  const float4 cv = *(const float4*)&c2[c];
  const float fv = f2[row];
  float4 o;
  o.x = -0.1f * sqrtf(fmaxf(fv + cv.x - 2.f * (p0.x + p1.x), 0.f));
  o.y = -0.1f * sqrtf(fmaxf(fv + cv.y - 2.f * (p0.y + p1.y), 0.f));
  o.z = -0.1f * sqrtf(fmaxf(fv + cv.z - 2.f * (p0.z + p1.z), 0.f));
  o.w = -0.1f * sqrtf(fmaxf(fv + cv.w - 2.f * (p0.w + p1.w), 0.f));
  *(float4*)&out[(size_t)row * NCLS + c] = o;
}

extern "C" void kernel_launch(void* const* d_in, const int* in_sizes, int n_in,
                              void* d_out, int out_size, void* d_ws, size_t ws_size,
                              hipStream_t stream) {
  const float* x    = (const float*)d_in[0];
  const float* x90  = (const float*)d_in[1];
  const float* x180 = (const float*)d_in[2];
  const float* x270 = (const float*)d_in[3];
  const float* W_f  = (const float*)d_in[4];
  const float* b_f  = (const float*)d_in[5];
  const float* W_r  = (const float*)d_in[6];
  const float* b_r  = (const float*)d_in[7];
  const float* cen  = (const float*)d_in[8];
  float* out = (float*)d_out;

  // workspace layout (bf16 as u16)
  u16* Xb = (u16*)d_ws;                         // [4][4096][1024]
  u16* Wb = Xb + 4ull * BSZ * INF;              // [2][512][1024]
  u16* Cb = Wb + 2ull * FEAT * INF;              // [1024][2048]
  u16* Fb = Cb + (size_t)NPAD * DTOT;           // [4096][2048]
  float* f2 = (float*)(Fb + (size_t)BSZ * DTOT);// [4096]
  float* c2 = f2 + BSZ;                         // [1024]
  float* P  = c2 + NPAD;                        // [2][4096][1024] fp32

  const int n8x = BSZ * INF / 8;   // 524288
  const int n8w = FEAT * INF / 8;  // 65536
  cvt_bf16_x4<<<dim3((n8x + 255) / 256, 4), 256, 0, stream>>>(x, x90, x180, x270,
                                                              Xb, n8x);
  cvt_bf16<<<(n8w + 255) / 256, 256, 0, stream>>>(W_f, Wb, n8w);
  cvt_bf16<<<(n8w + 255) / 256, 256, 0, stream>>>(W_r, Wb + (size_t)FEAT * INF, n8w);
  cvt_centers<<<NPAD, 256, 0, stream>>>(cen, Cb, c2);

  feat_gemm<<<512, 256, 0, stream>>>(Xb, Wb, b_f, b_r, Fb);
  row_sumsq<<<BSZ, 256, 0, stream>>>(Fb, f2);
  dist_gemm_sk<<<512, 256, 0, stream>>>(Fb, Cb, P);
  combine<<<BSZ, 256, 0, stream>>>(P, f2, c2, out);
}

// Round 8
// 86.911 us; speedup vs baseline: 1.0117x; 1.0117x over previous
//
#include <hip/hip_runtime.h>
#include <hip/hip_bf16.h>

typedef unsigned short u16;
typedef __attribute__((ext_vector_type(8))) short short8;
typedef __attribute__((ext_vector_type(4))) float f32x4;

#define BSZ   4096
#define INF   1024
#define FEAT  512
#define NCLS  1000
#define NPAD  1024
#define DTOT  2048

__device__ __forceinline__ u16 f2bf(float f) {
  unsigned int x = __float_as_uint(f);
  x += 0x7fffu + ((x >> 16) & 1u);   // RNE; inputs finite, no NaN path needed
  return (u16)(x >> 16);
}
__device__ __forceinline__ float bf2f(u16 h) {
  return __uint_as_float((unsigned int)h << 16);
}
__device__ __forceinline__ void gload_lds16(const void* g, void* l) {
  __builtin_amdgcn_global_load_lds(
      (const __attribute__((address_space(1))) void*)g,
      (__attribute__((address_space(3))) void*)l, 16, 0, 0);
}

// -------- fp32 -> bf16 convert for W_f / W_r (one dispatch, grid.y=2) ------
__global__ __launch_bounds__(256) void cvt_w2(const float* __restrict__ W_f,
                                              const float* __restrict__ W_r,
                                              u16* __restrict__ Wb, int n8) {
  int i = blockIdx.x * 256 + threadIdx.x;
  if (i >= n8) return;
  const float* in = blockIdx.y ? W_r : W_f;
  const float4* p = (const float4*)in;
  float4 a = p[2 * i], b = p[2 * i + 1];
  short8 o;
  o[0] = (short)f2bf(a.x); o[1] = (short)f2bf(a.y);
  o[2] = (short)f2bf(a.z); o[3] = (short)f2bf(a.w);
  o[4] = (short)f2bf(b.x); o[5] = (short)f2bf(b.y);
  o[6] = (short)f2bf(b.z); o[7] = (short)f2bf(b.w);
  *(short8*)&Wb[(size_t)blockIdx.y * n8 * 8 + (size_t)i * 8] = o;
}

// ------------- centers: convert to bf16 (padded to 1024 rows) + c2 ---------
__global__ __launch_bounds__(256) void cvt_centers(const float* __restrict__ cen,
                                                   u16* __restrict__ Cb,
                                                   float* __restrict__ c2) {
  const int row = blockIdx.x;   // 0..1023
  const int t = threadIdx.x;    // 256 threads, 8 elems each (D=2048)
  float s = 0.f;
  if (row < NCLS) {
    const float4* p = (const float4*)(cen + (size_t)row * DTOT) + 2 * t;
    float4 a = p[0], b = p[1];
    short8 o;
    o[0] = (short)f2bf(a.x); o[1] = (short)f2bf(a.y);
    o[2] = (short)f2bf(a.z); o[3] = (short)f2bf(a.w);
    o[4] = (short)f2bf(b.x); o[5] = (short)f2bf(b.y);
    o[6] = (short)f2bf(b.z); o[7] = (short)f2bf(b.w);
    *(short8*)&Cb[(size_t)row * DTOT + t * 8] = o;
    s = a.x * a.x + a.y * a.y + a.z * a.z + a.w * a.w +
        b.x * b.x + b.y * b.y + b.z * b.z + b.w * b.w;
  } else {
    short8 z = {0, 0, 0, 0, 0, 0, 0, 0};
    *(short8*)&Cb[(size_t)row * DTOT + t * 8] = z;
  }
#pragma unroll
  for (int o = 32; o > 0; o >>= 1) s += __shfl_xor(s, o);
  __shared__ float red[4];
  if ((t & 63) == 0) red[t >> 6] = s;
  __syncthreads();
  if (t == 0) c2[row] = red[0] + red[1] + red[2] + red[3];
}

// ---------------- per-row sum of squares over bf16 feat --------------------
__global__ __launch_bounds__(256) void row_sumsq(const u16* __restrict__ X,
                                                 float* __restrict__ f2) {
  const int row = blockIdx.x;
  const int t = threadIdx.x;
  short8 v = *(const short8*)&X[(size_t)row * DTOT + t * 8];
  float s = 0.f;
#pragma unroll
  for (int q = 0; q < 8; ++q) { float f = bf2f((u16)v[q]); s += f * f; }
#pragma unroll
  for (int o = 32; o > 0; o >>= 1) s += __shfl_xor(s, o);
  __shared__ float red[4];
  if ((t & 63) == 0) red[t >> 6] = s;
  __syncthreads();
  if (t == 0) f2[row] = red[0] + red[1] + red[2] + red[3];
}

// ---------------- feature GEMM with FUSED x fp32->bf16 convert -------------
// feat = relu(X @ W^T + b). 128x128 tile, 4 waves (2x2, wave 64x64), grid 512
// = 2 blocks/CU, XCD-chunked. A-operand: read x as fp32 float4 -> convert in
// reg -> ds_write_b128 (single-buffer As, XOR slot swizzle; T14: loads for
// t+1 issue before comp(t)). B-operand: global_load_lds from pre-converted
// Wb (double-buffered Bs). Kills the 100 MB cvt_x4 pass entirely.
__global__ __launch_bounds__(256) void feat_gemm(const float* __restrict__ x0,
                                                 const float* __restrict__ x1,
                                                 const float* __restrict__ x2,
                                                 const float* __restrict__ x3,
                                                 const u16* __restrict__ Wb,
                                                 const float* __restrict__ bf_,
                                                 const float* __restrict__ br_,
                                                 u16* __restrict__ Fb) {
  __shared__ u16 As[128 * 64];
  __shared__ u16 Bs[2][128 * 64];
  const int t = threadIdx.x;
  const int lane = t & 63;
  const int wid = t >> 6;
  const int wr = (wid >> 1) * 64;
  const int wc = (wid & 1) * 64;
  // XCD-chunked swizzle: 512 wgs -> 64 consecutive per XCD
  const int lid = blockIdx.x;
  const int swg = (lid & 7) * 64 + (lid >> 3);
  const int bm0 = (swg >> 4) * 128;      // M block
  const int n  = swg & 15;               // N block 0..15
  const int gc0 = n * 128;               // global feat col
  const int g = n >> 2;                  // quadrant 0..3
  const int bn0 = (n & 3) * 128;         // col within W
  const float* A = (g & 2) ? ((g & 1) ? x3 : x2) : ((g & 1) ? x1 : x0);
  const u16* Bt = Wb + (g ? (size_t)FEAT * INF : 0);
  const float* bias = g ? br_ : bf_;

  const int r8 = t >> 3;                          // staging row 0..31 (+32/it)
  const int kc  = (t & 7) << 3;                   // A: linear global k-chunk
  const int sws = (((t & 7) ^ (r8 & 7)) << 3);    // A: swizzled LDS dest slot
  const int kcs = sws;                            // B: swizzled global source
  const int l15 = lane & 15;
  const int l4 = lane >> 4;
  const int swz = l15 & 7;

  f32x4 acc[4][4] = {};
  float4 ar[8];

  auto ldA = [&](int k0) {
#pragma unroll
    for (int it = 0; it < 4; ++it) {
      const float* p = &A[(size_t)(bm0 + it * 32 + r8) * INF + k0 + kc];
      ar[2 * it]     = *(const float4*)p;
      ar[2 * it + 1] = *(const float4*)(p + 4);
    }
  };
  auto writeA = [&]() {
#pragma unroll
    for (int it = 0; it < 4; ++it) {
      short8 o;
      o[0] = (short)f2bf(ar[2 * it].x);     o[1] = (short)f2bf(ar[2 * it].y);
      o[2] = (short)f2bf(ar[2 * it].z);     o[3] = (short)f2bf(ar[2 * it].w);
      o[4] = (short)f2bf(ar[2 * it + 1].x); o[5] = (short)f2bf(ar[2 * it + 1].y);
      o[6] = (short)f2bf(ar[2 * it + 1].z); o[7] = (short)f2bf(ar[2 * it + 1].w);
      *(short8*)&As[(it * 32 + r8) * 64 + sws] = o;
    }
  };
  auto stageB = [&](int buf, int k0) {
#pragma unroll
    for (int it = 0; it < 4; ++it)
      gload_lds16(&Bt[(size_t)(bn0 + it * 32 + r8) * INF + k0 + kcs],
                  &Bs[buf][(it * 256 + (wid << 6)) * 8]);
  };
  auto comp = [&](int buf) {
#pragma unroll
    for (int ks = 0; ks < 2; ++ks) {
      const int so = (((ks * 4 + l4) ^ swz) << 3);
      short8 av[4], bv[4];
#pragma unroll
      for (int i = 0; i < 4; ++i)
        av[i] = *(const short8*)&As[(wr + i * 16 + l15) * 64 + so];
#pragma unroll
      for (int j = 0; j < 4; ++j)
        bv[j] = *(const short8*)&Bs[buf][(wc + j * 16 + l15) * 64 + so];
#pragma unroll
      for (int i = 0; i < 4; ++i)
#pragma unroll
        for (int j = 0; j < 4; ++j)
          acc[i][j] = __builtin_amdgcn_mfma_f32_16x16x32_bf16(av[i], bv[j],
                                                              acc[i][j], 0, 0, 0);
    }
  };

  const int NT = INF / 64;   // 16
  ldA(0);
  stageB(0, 0);
  writeA();
  __syncthreads();           // drains B gload_lds + As writes
  for (int tt = 0; tt < NT; ++tt) {
    if (tt + 1 < NT) {
      ldA((tt + 1) * 64);                 // fp32 loads in flight over comp
      stageB((tt + 1) & 1, (tt + 1) * 64);
    }
    comp(tt & 1);
    __syncthreads();         // all waves done reading As(tt)
    if (tt + 1 < NT) writeA();
    __syncthreads();         // As(tt+1) visible; Bs(tt+1) drained
  }

#pragma unroll
  for (int j = 0; j < 4; ++j) {
    const int col = gc0 + wc + j * 16 + l15;
    const float bval = bias[bn0 + wc + j * 16 + l15];
#pragma unroll
    for (int i = 0; i < 4; ++i) {
#pragma unroll
      for (int r = 0; r < 4; ++r) {
        const int row = bm0 + wr + i * 16 + l4 * 4 + r;
        float v = fmaxf(acc[i][j][r] + bval, 0.f);
        Fb[(size_t)row * DTOT + col] = f2bf(v);
      }
    }
  }
}

// ---- distance GEMM split-K: P[k] = feat[:, k*1024:(k+1)*1024] @ Cb^T ------
// 128x128 tile, dbuf, grid 32m x 8n x 2k = 512 blocks = 2/CU.
__global__ __launch_bounds__(256) void dist_gemm_sk(const u16* __restrict__ Fb,
                                                    const u16* __restrict__ Cb,
                                                    float* __restrict__ P) {
  __shared__ u16 As[2][128 * 64];
  __shared__ u16 Bs[2][128 * 64];
  const int t = threadIdx.x;
  const int lane = t & 63;
  const int wid = t >> 6;
  const int wr = (wid >> 1) * 64;
  const int wc = (wid & 1) * 64;
  const int lid = blockIdx.x;
  const int swg = (lid & 7) * 64 + (lid >> 3);
  const int n = swg & 7;                 // 0..7
  const int kidx = (swg >> 3) & 1;       // K split 0..1
  const int bm0 = (swg >> 4) * 128;      // 0..31 -> rows
  const int bn0 = n * 128;               // padded class col
  const int kbase = kidx * 1024;

  const int r8 = t >> 3;
  const int kcs = (((t & 7) ^ (r8 & 7)) << 3);
  const int l15 = lane & 15;
  const int l4 = lane >> 4;
  const int swz = l15 & 7;

  f32x4 acc[4][4] = {};

  auto stage = [&](int buf, int k0) {
#pragma unroll
    for (int it = 0; it < 4; ++it) {
      gload_lds16(&Fb[(size_t)(bm0 + it * 32 + r8) * DTOT + k0 + kcs],
                  &As[buf][(it * 256 + (wid << 6)) * 8]);
      gload_lds16(&Cb[(size_t)(bn0 + it * 32 + r8) * DTOT + k0 + kcs],
                  &Bs[buf][(it * 256 + (wid << 6)) * 8]);
    }
  };
  auto comp = [&](int buf) {
#pragma unroll
    for (int ks = 0; ks < 2; ++ks) {
      const int so = (((ks * 4 + l4) ^ swz) << 3);
      short8 av[4], bv[4];
#pragma unroll
      for (int i = 0; i < 4; ++i)
        av[i] = *(const short8*)&As[buf][(wr + i * 16 + l15) * 64 + so];
#pragma unroll
      for (int j = 0; j < 4; ++j)
        bv[j] = *(const short8*)&Bs[buf][(wc + j * 16 + l15) * 64 + so];
#pragma unroll
      for (int i = 0; i < 4; ++i)
#pragma unroll
        for (int j = 0; j < 4; ++j)
          acc[i][j] = __builtin_amdgcn_mfma_f32_16x16x32_bf16(av[i], bv[j],
                                                              acc[i][j], 0, 0, 0);
    }
  };

  stage(0, kbase);
  __syncthreads();
  for (int k0 = kbase; k0 < kbase + 1024; k0 += 128) {
    stage(1, k0 + 64);
    comp(0);
    __syncthreads();
    if (k0 + 128 < kbase + 1024) stage(0, k0 + 128);
    comp(1);
    __syncthreads();
  }

  float* Pk = P + (size_t)kidx * BSZ * NPAD;
#pragma unroll
  for (int j = 0; j < 4; ++j) {
    const int col = bn0 + wc + j * 16 + l15;
#pragma unroll
    for (int i = 0; i < 4; ++i) {
#pragma unroll
      for (int r = 0; r < 4; ++r) {
        const int row = bm0 + wr + i * 16 + l4 * 4 + r;
        Pk[(size_t)row * NPAD + col] = acc[i][j][r];
      }
    }
  }
}

// ------ combine: out = -0.1*sqrt(max(f2 + c2 - 2*(P0+P1), 0)) --------------
__global__ __launch_bounds__(256) void combine(const float* __restrict__ P,
                                               const float* __restrict__ f2,
                                               const float* __restrict__ c2,
                                               float* __restrict__ out) {
  const int row = blockIdx.x;
  const int c = threadIdx.x * 4;
  if (c >= NCLS) return;
  const float4 p0 = *(const float4*)&P[(size_t)row * NPAD + c];
  const float4 p1 = *(const float4*)&P[(size_t)(BSZ + row) * NPAD + c];
  const float4 cv = *(const float4*)&c2[c];
  const float fv = f2[row];
  float4 o;
  o.x = -0.1f * sqrtf(fmaxf(fv + cv.x - 2.f * (p0.x + p1.x), 0.f));
  o.y = -0.1f * sqrtf(fmaxf(fv + cv.y - 2.f * (p0.y + p1.y), 0.f));
  o.z = -0.1f * sqrtf(fmaxf(fv + cv.z - 2.f * (p0.z + p1.z), 0.f));
  o.w = -0.1f * sqrtf(fmaxf(fv + cv.w - 2.f * (p0.w + p1.w), 0.f));
  *(float4*)&out[(size_t)row * NCLS + c] = o;
}

extern "C" void kernel_launch(void* const* d_in, const int* in_sizes, int n_in,
                              void* d_out, int out_size, void* d_ws, size_t ws_size,
                              hipStream_t stream) {
  const float* x    = (const float*)d_in[0];
  const float* x90  = (const float*)d_in[1];
  const float* x180 = (const float*)d_in[2];
  const float* x270 = (const float*)d_in[3];
  const float* W_f  = (const float*)d_in[4];
  const float* b_f  = (const float*)d_in[5];
  const float* W_r  = (const float*)d_in[6];
  const float* b_r  = (const float*)d_in[7];
  const float* cen  = (const float*)d_in[8];
  float* out = (float*)d_out;

  // workspace layout (bf16 as u16); Xb eliminated (convert fused into feat)
  u16* Wb = (u16*)d_ws;                         // [2][512][1024]
  u16* Cb = Wb + 2ull * FEAT * INF;             // [1024][2048]
  u16* Fb = Cb + (size_t)NPAD * DTOT;           // [4096][2048]
  float* f2 = (float*)(Fb + (size_t)BSZ * DTOT);// [4096]
  float* c2 = f2 + BSZ;                         // [1024]
  float* P  = c2 + NPAD;                        // [2][4096][1024] fp32

  const int n8w = FEAT * INF / 8;  // 65536
  cvt_w2<<<dim3((n8w + 255) / 256, 2), 256, 0, stream>>>(W_f, W_r, Wb, n8w);
  cvt_centers<<<NPAD, 256, 0, stream>>>(cen, Cb, c2);

  feat_gemm<<<512, 256, 0, stream>>>(x, x90, x180, x270, Wb, b_f, b_r, Fb);
  row_sumsq<<<BSZ, 256, 0, stream>>>(Fb, f2);
  dist_gemm_sk<<<512, 256, 0, stream>>>(Fb, Cb, P);
  combine<<<BSZ, 256, 0, stream>>>(P, f2, c2, out);
}

// Round 9
// 86.616 us; speedup vs baseline: 1.0151x; 1.0034x over previous
//
#include <hip/hip_runtime.h>
#include <hip/hip_bf16.h>

typedef unsigned short u16;
typedef __attribute__((ext_vector_type(8))) short short8;
typedef __attribute__((ext_vector_type(4))) float f32x4;

#define BSZ   4096
#define INF   1024
#define FEAT  512
#define NCLS  1000
#define NPAD  1024
#define DTOT  2048

__device__ __forceinline__ u16 f2bf(float f) {
  unsigned int x = __float_as_uint(f);
  x += 0x7fffu + ((x >> 16) & 1u);   // RNE; inputs finite, no NaN path needed
  return (u16)(x >> 16);
}
__device__ __forceinline__ float bf2f(u16 h) {
  return __uint_as_float((unsigned int)h << 16);
}
__device__ __forceinline__ void gload_lds16(const void* g, void* l) {
  __builtin_amdgcn_global_load_lds(
      (const __attribute__((address_space(1))) void*)g,
      (__attribute__((address_space(3))) void*)l, 16, 0, 0);
}

// -------- fp32 -> bf16 convert for W_f / W_r (one dispatch, grid.y=2) ------
__global__ __launch_bounds__(256) void cvt_w2(const float* __restrict__ W_f,
                                              const float* __restrict__ W_r,
                                              u16* __restrict__ Wb, int n8) {
  int i = blockIdx.x * 256 + threadIdx.x;
  if (i >= n8) return;
  const float* in = blockIdx.y ? W_r : W_f;
  const float4* p = (const float4*)in;
  float4 a = p[2 * i], b = p[2 * i + 1];
  short8 o;
  o[0] = (short)f2bf(a.x); o[1] = (short)f2bf(a.y);
  o[2] = (short)f2bf(a.z); o[3] = (short)f2bf(a.w);
  o[4] = (short)f2bf(b.x); o[5] = (short)f2bf(b.y);
  o[6] = (short)f2bf(b.z); o[7] = (short)f2bf(b.w);
  *(short8*)&Wb[(size_t)blockIdx.y * n8 * 8 + (size_t)i * 8] = o;
}

// ------------- centers: convert to bf16 (padded to 1024 rows) + c2 ---------
__global__ __launch_bounds__(256) void cvt_centers(const float* __restrict__ cen,
                                                   u16* __restrict__ Cb,
                                                   float* __restrict__ c2) {
  const int row = blockIdx.x;   // 0..1023
  const int t = threadIdx.x;    // 256 threads, 8 elems each (D=2048)
  float s = 0.f;
  if (row < NCLS) {
    const float4* p = (const float4*)(cen + (size_t)row * DTOT) + 2 * t;
    float4 a = p[0], b = p[1];
    short8 o;
    o[0] = (short)f2bf(a.x); o[1] = (short)f2bf(a.y);
    o[2] = (short)f2bf(a.z); o[3] = (short)f2bf(a.w);
    o[4] = (short)f2bf(b.x); o[5] = (short)f2bf(b.y);
    o[6] = (short)f2bf(b.z); o[7] = (short)f2bf(b.w);
    *(short8*)&Cb[(size_t)row * DTOT + t * 8] = o;
    s = a.x * a.x + a.y * a.y + a.z * a.z + a.w * a.w +
        b.x * b.x + b.y * b.y + b.z * b.z + b.w * b.w;
  } else {
    short8 z = {0, 0, 0, 0, 0, 0, 0, 0};
    *(short8*)&Cb[(size_t)row * DTOT + t * 8] = z;
  }
#pragma unroll
  for (int o = 32; o > 0; o >>= 1) s += __shfl_xor(s, o);
  __shared__ float red[4];
  if ((t & 63) == 0) red[t >> 6] = s;
  __syncthreads();
  if (t == 0) c2[row] = red[0] + red[1] + red[2] + red[3];
}

// ---------------- feature GEMM with FUSED x fp32->bf16 convert -------------
// feat = relu(X @ W^T + b). 128x128 tile, 4 waves (2x2, wave 64x64), grid 512
// = 2 blocks/CU, XCD-chunked. BOTH operands double-buffered (64 KB LDS):
// per iter {ldA(t+1); stageB(t+1); comp(t); writeA(t+1); ONE barrier}.
// (R8's single-buffer As needed 2 barriers with writeA serialized alone
// between them -> +14us. writeA now targets the other buffer: no extra
// barrier, ldA latency hidden under comp's MFMAs.)
__global__ __launch_bounds__(256) void feat_gemm(const float* __restrict__ x0,
                                                 const float* __restrict__ x1,
                                                 const float* __restrict__ x2,
                                                 const float* __restrict__ x3,
                                                 const u16* __restrict__ Wb,
                                                 const float* __restrict__ bf_,
                                                 const float* __restrict__ br_,
                                                 u16* __restrict__ Fb) {
  __shared__ u16 As[2][128 * 64];
  __shared__ u16 Bs[2][128 * 64];
  const int t = threadIdx.x;
  const int lane = t & 63;
  const int wid = t >> 6;
  const int wr = (wid >> 1) * 64;
  const int wc = (wid & 1) * 64;
  // XCD-chunked swizzle: 512 wgs -> 64 consecutive per XCD
  const int lid = blockIdx.x;
  const int swg = (lid & 7) * 64 + (lid >> 3);
  const int bm0 = (swg >> 4) * 128;      // M block
  const int n  = swg & 15;               // N block 0..15
  const int gc0 = n * 128;               // global feat col
  const int g = n >> 2;                  // quadrant 0..3
  const int bn0 = (n & 3) * 128;         // col within W
  const float* A = (g & 2) ? ((g & 1) ? x3 : x2) : ((g & 1) ? x1 : x0);
  const u16* Bt = Wb + (g ? (size_t)FEAT * INF : 0);
  const float* bias = g ? br_ : bf_;

  const int r8 = t >> 3;                          // staging row 0..31 (+32/it)
  const int kc  = (t & 7) << 3;                   // A: linear global k-chunk
  const int sws = (((t & 7) ^ (r8 & 7)) << 3);    // A: swizzled LDS dest slot
  const int kcs = sws;                            // B: swizzled global source
  const int l15 = lane & 15;
  const int l4 = lane >> 4;
  const int swz = l15 & 7;

  f32x4 acc[4][4] = {};
  float4 ar[8];

  auto ldA = [&](int k0) {
#pragma unroll
    for (int it = 0; it < 4; ++it) {
      const float* p = &A[(size_t)(bm0 + it * 32 + r8) * INF + k0 + kc];
      ar[2 * it]     = *(const float4*)p;
      ar[2 * it + 1] = *(const float4*)(p + 4);
    }
  };
  auto writeA = [&](int buf) {
#pragma unroll
    for (int it = 0; it < 4; ++it) {
      short8 o;
      o[0] = (short)f2bf(ar[2 * it].x);     o[1] = (short)f2bf(ar[2 * it].y);
      o[2] = (short)f2bf(ar[2 * it].z);     o[3] = (short)f2bf(ar[2 * it].w);
      o[4] = (short)f2bf(ar[2 * it + 1].x); o[5] = (short)f2bf(ar[2 * it + 1].y);
      o[6] = (short)f2bf(ar[2 * it + 1].z); o[7] = (short)f2bf(ar[2 * it + 1].w);
      *(short8*)&As[buf][(it * 32 + r8) * 64 + sws] = o;
    }
  };
  auto stageB = [&](int buf, int k0) {
#pragma unroll
    for (int it = 0; it < 4; ++it)
      gload_lds16(&Bt[(size_t)(bn0 + it * 32 + r8) * INF + k0 + kcs],
                  &Bs[buf][(it * 256 + (wid << 6)) * 8]);
  };
  auto comp = [&](int buf) {
#pragma unroll
    for (int ks = 0; ks < 2; ++ks) {
      const int so = (((ks * 4 + l4) ^ swz) << 3);
      short8 av[4], bv[4];
#pragma unroll
      for (int i = 0; i < 4; ++i)
        av[i] = *(const short8*)&As[buf][(wr + i * 16 + l15) * 64 + so];
#pragma unroll
      for (int j = 0; j < 4; ++j)
        bv[j] = *(const short8*)&Bs[buf][(wc + j * 16 + l15) * 64 + so];
#pragma unroll
      for (int i = 0; i < 4; ++i)
#pragma unroll
        for (int j = 0; j < 4; ++j)
          acc[i][j] = __builtin_amdgcn_mfma_f32_16x16x32_bf16(av[i], bv[j],
                                                              acc[i][j], 0, 0, 0);
    }
  };

  const int NT = INF / 64;   // 16
  ldA(0);
  stageB(0, 0);
  writeA(0);
  __syncthreads();           // buf 0 ready (gload_lds drained, ds_writes done)
  for (int tt = 0; tt < NT; ++tt) {
    const int cur = tt & 1, nxt = cur ^ 1;
    if (tt + 1 < NT) {
      ldA((tt + 1) * 64);                 // fp32 loads in flight over comp
      stageB(nxt, (tt + 1) * 64);
    }
    comp(cur);
    if (tt + 1 < NT) writeA(nxt);         // other buffer: no barrier needed
    __syncthreads();                      // seals buf nxt for next iter
  }

#pragma unroll
  for (int j = 0; j < 4; ++j) {
    const int col = gc0 + wc + j * 16 + l15;
    const float bval = bias[bn0 + wc + j * 16 + l15];
#pragma unroll
    for (int i = 0; i < 4; ++i) {
#pragma unroll
      for (int r = 0; r < 4; ++r) {
        const int row = bm0 + wr + i * 16 + l4 * 4 + r;
        float v = fmaxf(acc[i][j][r] + bval, 0.f);
        Fb[(size_t)row * DTOT + col] = f2bf(v);
      }
    }
  }
}

// ---- distance GEMM split-K: P[k] = feat[:, k*1024:(k+1)*1024] @ Cb^T ------
// 128x128 tile, dbuf, grid 32m x 8n x 2k = 512 blocks = 2/CU.
__global__ __launch_bounds__(256) void dist_gemm_sk(const u16* __restrict__ Fb,
                                                    const u16* __restrict__ Cb,
                                                    float* __restrict__ P) {
  __shared__ u16 As[2][128 * 64];
  __shared__ u16 Bs[2][128 * 64];
  const int t = threadIdx.x;
  const int lane = t & 63;
  const int wid = t >> 6;
  const int wr = (wid >> 1) * 64;
  const int wc = (wid & 1) * 64;
  const int lid = blockIdx.x;
  const int swg = (lid & 7) * 64 + (lid >> 3);
  const int n = swg & 7;                 // 0..7
  const int kidx = (swg >> 3) & 1;       // K split 0..1
  const int bm0 = (swg >> 4) * 128;      // 0..31 -> rows
  const int bn0 = n * 128;               // padded class col
  const int kbase = kidx * 1024;

  const int r8 = t >> 3;
  const int kcs = (((t & 7) ^ (r8 & 7)) << 3);
  const int l15 = lane & 15;
  const int l4 = lane >> 4;
  const int swz = l15 & 7;

  f32x4 acc[4][4] = {};

  auto stage = [&](int buf, int k0) {
#pragma unroll
    for (int it = 0; it < 4; ++it) {
      gload_lds16(&Fb[(size_t)(bm0 + it * 32 + r8) * DTOT + k0 + kcs],
                  &As[buf][(it * 256 + (wid << 6)) * 8]);
      gload_lds16(&Cb[(size_t)(bn0 + it * 32 + r8) * DTOT + k0 + kcs],
                  &Bs[buf][(it * 256 + (wid << 6)) * 8]);
    }
  };
  auto comp = [&](int buf) {
#pragma unroll
    for (int ks = 0; ks < 2; ++ks) {
      const int so = (((ks * 4 + l4) ^ swz) << 3);
      short8 av[4], bv[4];
#pragma unroll
      for (int i = 0; i < 4; ++i)
        av[i] = *(const short8*)&As[buf][(wr + i * 16 + l15) * 64 + so];
#pragma unroll
      for (int j = 0; j < 4; ++j)
        bv[j] = *(const short8*)&Bs[buf][(wc + j * 16 + l15) * 64 + so];
#pragma unroll
      for (int i = 0; i < 4; ++i)
#pragma unroll
        for (int j = 0; j < 4; ++j)
          acc[i][j] = __builtin_amdgcn_mfma_f32_16x16x32_bf16(av[i], bv[j],
                                                              acc[i][j], 0, 0, 0);
    }
  };

  stage(0, kbase);
  __syncthreads();
  for (int k0 = kbase; k0 < kbase + 1024; k0 += 128) {
    stage(1, k0 + 64);
    comp(0);
    __syncthreads();
    if (k0 + 128 < kbase + 1024) stage(0, k0 + 128);
    comp(1);
    __syncthreads();
  }

  float* Pk = P + (size_t)kidx * BSZ * NPAD;
#pragma unroll
  for (int j = 0; j < 4; ++j) {
    const int col = bn0 + wc + j * 16 + l15;
#pragma unroll
    for (int i = 0; i < 4; ++i) {
#pragma unroll
      for (int r = 0; r < 4; ++r) {
        const int row = bm0 + wr + i * 16 + l4 * 4 + r;
        Pk[(size_t)row * NPAD + col] = acc[i][j][r];
      }
    }
  }
}

// ------ combine (fused f2): f2 = ||Fb[row]||^2 computed in-block, then
//        out = -0.1*sqrt(max(f2 + c2 - 2*(P0+P1), 0)). One block per row.
__global__ __launch_bounds__(256) void combine(const u16* __restrict__ Fb,
                                               const float* __restrict__ P,
                                               const float* __restrict__ c2,
                                               float* __restrict__ out) {
  const int row = blockIdx.x;
  const int t = threadIdx.x;
  // f2 reduction over the row's 2048 bf16 (8 per thread)
  short8 v = *(const short8*)&Fb[(size_t)row * DTOT + t * 8];
  float s = 0.f;
#pragma unroll
  for (int q = 0; q < 8; ++q) { float f = bf2f((u16)v[q]); s += f * f; }
#pragma unroll
  for (int o = 32; o > 0; o >>= 1) s += __shfl_xor(s, o);
  __shared__ float red[4];
  if ((t & 63) == 0) red[t >> 6] = s;
  __syncthreads();
  const float fv = red[0] + red[1] + red[2] + red[3];

  const int c = t * 4;
  if (c >= NCLS) return;
  const float4 p0 = *(const float4*)&P[(size_t)row * NPAD + c];
  const float4 p1 = *(const float4*)&P[(size_t)(BSZ + row) * NPAD + c];
  const float4 cv = *(const float4*)&c2[c];
  float4 o;
  o.x = -0.1f * sqrtf(fmaxf(fv + cv.x - 2.f * (p0.x + p1.x), 0.f));
  o.y = -0.1f * sqrtf(fmaxf(fv + cv.y - 2.f * (p0.y + p1.y), 0.f));
  o.z = -0.1f * sqrtf(fmaxf(fv + cv.z - 2.f * (p0.z + p1.z), 0.f));
  o.w = -0.1f * sqrtf(fmaxf(fv + cv.w - 2.f * (p0.w + p1.w), 0.f));
  *(float4*)&out[(size_t)row * NCLS + c] = o;
}

extern "C" void kernel_launch(void* const* d_in, const int* in_sizes, int n_in,
                              void* d_out, int out_size, void* d_ws, size_t ws_size,
                              hipStream_t stream) {
  const float* x    = (const float*)d_in[0];
  const float* x90  = (const float*)d_in[1];
  const float* x180 = (const float*)d_in[2];
  const float* x270 = (const float*)d_in[3];
  const float* W_f  = (const float*)d_in[4];
  const float* b_f  = (const float*)d_in[5];
  const float* W_r  = (const float*)d_in[6];
  const float* b_r  = (const float*)d_in[7];
  const float* cen  = (const float*)d_in[8];
  float* out = (float*)d_out;

  // workspace layout (bf16 as u16); Xb eliminated (convert fused into feat)
  u16* Wb = (u16*)d_ws;                         // [2][512][1024]
  u16* Cb = Wb + 2ull * FEAT * INF;             // [1024][2048]
  u16* Fb = Cb + (size_t)NPAD * DTOT;           // [4096][2048]
  float* c2 = (float*)(Fb + (size_t)BSZ * DTOT);// [1024]
  float* P  = c2 + NPAD;                        // [2][4096][1024] fp32

  const int n8w = FEAT * INF / 8;  // 65536
  cvt_w2<<<dim3((n8w + 255) / 256, 2), 256, 0, stream>>>(W_f, W_r, Wb, n8w);
  cvt_centers<<<NPAD, 256, 0, stream>>>(cen, Cb, c2);

  feat_gemm<<<512, 256, 0, stream>>>(x, x90, x180, x270, Wb, b_f, b_r, Fb);
  dist_gemm_sk<<<512, 256, 0, stream>>>(Fb, Cb, P);
  combine<<<BSZ, 256, 0, stream>>>(Fb, P, c2, out);
}

// Round 10
// 72.594 us; speedup vs baseline: 1.2112x; 1.1932x over previous
//
#include <hip/hip_runtime.h>
#include <hip/hip_bf16.h>

typedef unsigned short u16;
typedef unsigned int u32;
typedef __attribute__((ext_vector_type(8))) short short8;
typedef __attribute__((ext_vector_type(4))) short short4v;
typedef __attribute__((ext_vector_type(4))) float f32x4;
typedef __attribute__((ext_vector_type(4))) unsigned int u32x4;

#define BSZ   4096
#define INF   1024
#define FEAT  512
#define NCLS  1000
#define NPAD  1024
#define DTOT  2048

__device__ __forceinline__ u16 f2bf(float f) {
  unsigned int x = __float_as_uint(f);
  x += 0x7fffu + ((x >> 16) & 1u);   // RNE
  return (u16)(x >> 16);
}
__device__ __forceinline__ float bf2f(u16 h) {
  return __uint_as_float((unsigned int)h << 16);
}
// packed f32x2 -> bf16x2 (RNE), single VALU op (T12 recipe, m214v22-verified)
__device__ __forceinline__ u32 cvt_pk(float lo, float hi) {
  u32 r;
  asm("v_cvt_pk_bf16_f32 %0, %1, %2" : "=v"(r) : "v"(lo), "v"(hi));
  return r;
}
__device__ __forceinline__ void gload_lds16(const void* g, void* l) {
  __builtin_amdgcn_global_load_lds(
      (const __attribute__((address_space(1))) void*)g,
      (__attribute__((address_space(3))) void*)l, 16, 0, 0);
}

// ---- fused prep: W_f/W_r convert (blocks 0..511) + centers+c2 (512..1535) --
__global__ __launch_bounds__(256) void cvt_prep(const float* __restrict__ W_f,
                                                const float* __restrict__ W_r,
                                                const float* __restrict__ cen,
                                                u16* __restrict__ Wb,
                                                u16* __restrict__ Cb,
                                                float* __restrict__ c2) {
  const int b = blockIdx.x;
  const int t = threadIdx.x;
  if (b < 512) {                       // W convert: 2 x 512x1024
    const int half = b >> 8;           // 0: W_f, 1: W_r
    const int i = (b & 255) * 256 + t; // 0..65535
    const float* in = half ? W_r : W_f;
    const float4* p = (const float4*)in;
    float4 a = p[2 * i], bb = p[2 * i + 1];
    u32x4 o;
    o[0] = cvt_pk(a.x, a.y);  o[1] = cvt_pk(a.z, a.w);
    o[2] = cvt_pk(bb.x, bb.y); o[3] = cvt_pk(bb.z, bb.w);
    *(u32x4*)&Wb[(size_t)half * FEAT * INF + (size_t)i * 8] = o;
    return;
  }
  const int row = b - 512;             // 0..1023
  float s = 0.f;
  if (row < NCLS) {
    const float4* p = (const float4*)(cen + (size_t)row * DTOT) + 2 * t;
    float4 a = p[0], bb = p[1];
    u32x4 o;
    o[0] = cvt_pk(a.x, a.y);  o[1] = cvt_pk(a.z, a.w);
    o[2] = cvt_pk(bb.x, bb.y); o[3] = cvt_pk(bb.z, bb.w);
    *(u32x4*)&Cb[(size_t)row * DTOT + t * 8] = o;
    s = a.x * a.x + a.y * a.y + a.z * a.z + a.w * a.w +
        bb.x * bb.x + bb.y * bb.y + bb.z * bb.z + bb.w * bb.w;
  } else {
    u32x4 z = {0, 0, 0, 0};
    *(u32x4*)&Cb[(size_t)row * DTOT + t * 8] = z;
  }
#pragma unroll
  for (int o = 32; o > 0; o >>= 1) s += __shfl_xor(s, o);
  __shared__ float red[4];
  if ((t & 63) == 0) red[t >> 6] = s;
  __syncthreads();
  if (t == 0) c2[row] = red[0] + red[1] + red[2] + red[3];
}

// ---------------- feature GEMM with FUSED x fp32->bf16 convert -------------
// 128x128 tile, 4 waves, both operands dbuf, one barrier/K-step (R9), but
// conversion now via v_cvt_pk_bf16_f32 (1 op / 2 elems vs 4 ops/elem).
__global__ __launch_bounds__(256) void feat_gemm(const float* __restrict__ x0,
                                                 const float* __restrict__ x1,
                                                 const float* __restrict__ x2,
                                                 const float* __restrict__ x3,
                                                 const u16* __restrict__ Wb,
                                                 const float* __restrict__ bf_,
                                                 const float* __restrict__ br_,
                                                 u16* __restrict__ Fb) {
  __shared__ u16 As[2][128 * 64];
  __shared__ u16 Bs[2][128 * 64];
  const int t = threadIdx.x;
  const int lane = t & 63;
  const int wid = t >> 6;
  const int wr = (wid >> 1) * 64;
  const int wc = (wid & 1) * 64;
  const int lid = blockIdx.x;
  const int swg = (lid & 7) * 64 + (lid >> 3);
  const int bm0 = (swg >> 4) * 128;      // M block
  const int n  = swg & 15;               // N block 0..15
  const int gc0 = n * 128;               // global feat col
  const int g = n >> 2;                  // quadrant 0..3
  const int bn0 = (n & 3) * 128;         // col within W
  const float* A = (g & 2) ? ((g & 1) ? x3 : x2) : ((g & 1) ? x1 : x0);
  const u16* Bt = Wb + (g ? (size_t)FEAT * INF : 0);
  const float* bias = g ? br_ : bf_;

  const int r8 = t >> 3;
  const int kc  = (t & 7) << 3;                   // A: linear global k-chunk
  const int sws = (((t & 7) ^ (r8 & 7)) << 3);    // A: swizzled LDS dest slot
  const int kcs = sws;                            // B: swizzled global source
  const int l15 = lane & 15;
  const int l4 = lane >> 4;
  const int swz = l15 & 7;

  f32x4 acc[4][4] = {};
  float4 ar[8];

  auto ldA = [&](int k0) {
#pragma unroll
    for (int it = 0; it < 4; ++it) {
      const float* p = &A[(size_t)(bm0 + it * 32 + r8) * INF + k0 + kc];
      ar[2 * it]     = *(const float4*)p;
      ar[2 * it + 1] = *(const float4*)(p + 4);
    }
  };
  auto writeA = [&](int buf) {
#pragma unroll
    for (int it = 0; it < 4; ++it) {
      u32x4 o;
      o[0] = cvt_pk(ar[2 * it].x, ar[2 * it].y);
      o[1] = cvt_pk(ar[2 * it].z, ar[2 * it].w);
      o[2] = cvt_pk(ar[2 * it + 1].x, ar[2 * it + 1].y);
      o[3] = cvt_pk(ar[2 * it + 1].z, ar[2 * it + 1].w);
      *(u32x4*)&As[buf][(it * 32 + r8) * 64 + sws] = o;
    }
  };
  auto stageB = [&](int buf, int k0) {
#pragma unroll
    for (int it = 0; it < 4; ++it)
      gload_lds16(&Bt[(size_t)(bn0 + it * 32 + r8) * INF + k0 + kcs],
                  &Bs[buf][(it * 256 + (wid << 6)) * 8]);
  };
  auto comp = [&](int buf) {
#pragma unroll
    for (int ks = 0; ks < 2; ++ks) {
      const int so = (((ks * 4 + l4) ^ swz) << 3);
      short8 av[4], bv[4];
#pragma unroll
      for (int i = 0; i < 4; ++i)
        av[i] = *(const short8*)&As[buf][(wr + i * 16 + l15) * 64 + so];
#pragma unroll
      for (int j = 0; j < 4; ++j)
        bv[j] = *(const short8*)&Bs[buf][(wc + j * 16 + l15) * 64 + so];
#pragma unroll
      for (int i = 0; i < 4; ++i)
#pragma unroll
        for (int j = 0; j < 4; ++j)
          acc[i][j] = __builtin_amdgcn_mfma_f32_16x16x32_bf16(av[i], bv[j],
                                                              acc[i][j], 0, 0, 0);
    }
  };

  const int NT = INF / 64;   // 16
  ldA(0);
  stageB(0, 0);
  writeA(0);
  __syncthreads();
  for (int tt = 0; tt < NT; ++tt) {
    const int cur = tt & 1, nxt = cur ^ 1;
    if (tt + 1 < NT) {
      ldA((tt + 1) * 64);
      stageB(nxt, (tt + 1) * 64);
    }
    comp(cur);
    if (tt + 1 < NT) writeA(nxt);
    __syncthreads();
  }

#pragma unroll
  for (int j = 0; j < 4; ++j) {
    const int col = gc0 + wc + j * 16 + l15;
    const float bval = bias[bn0 + wc + j * 16 + l15];
#pragma unroll
    for (int i = 0; i < 4; ++i) {
#pragma unroll
      for (int r = 0; r < 4; ++r) {
        const int row = bm0 + wr + i * 16 + l4 * 4 + r;
        float v = fmaxf(acc[i][j][r] + bval, 0.f);
        Fb[(size_t)row * DTOT + col] = f2bf(v);
      }
    }
  }
}

// ---- distance GEMM split-K: P[k] = feat[:, k*1024:(k+1)*1024] @ Cb^T ------
// 128x128 tile, dbuf, grid 512 = 2/CU. P stored BF16 (halves combine traffic;
// |P|<~50, bf16 rel err 0.4% -> d2 error ~0.2 vs budget ~70).
__global__ __launch_bounds__(256) void dist_gemm_sk(const u16* __restrict__ Fb,
                                                    const u16* __restrict__ Cb,
                                                    u16* __restrict__ P) {
  __shared__ u16 As[2][128 * 64];
  __shared__ u16 Bs[2][128 * 64];
  const int t = threadIdx.x;
  const int lane = t & 63;
  const int wid = t >> 6;
  const int wr = (wid >> 1) * 64;
  const int wc = (wid & 1) * 64;
  const int lid = blockIdx.x;
  const int swg = (lid & 7) * 64 + (lid >> 3);
  const int n = swg & 7;
  const int kidx = (swg >> 3) & 1;
  const int bm0 = (swg >> 4) * 128;
  const int bn0 = n * 128;
  const int kbase = kidx * 1024;

  const int r8 = t >> 3;
  const int kcs = (((t & 7) ^ (r8 & 7)) << 3);
  const int l15 = lane & 15;
  const int l4 = lane >> 4;
  const int swz = l15 & 7;

  f32x4 acc[4][4] = {};

  auto stage = [&](int buf, int k0) {
#pragma unroll
    for (int it = 0; it < 4; ++it) {
      gload_lds16(&Fb[(size_t)(bm0 + it * 32 + r8) * DTOT + k0 + kcs],
                  &As[buf][(it * 256 + (wid << 6)) * 8]);
      gload_lds16(&Cb[(size_t)(bn0 + it * 32 + r8) * DTOT + k0 + kcs],
                  &Bs[buf][(it * 256 + (wid << 6)) * 8]);
    }
  };
  auto comp = [&](int buf) {
#pragma unroll
    for (int ks = 0; ks < 2; ++ks) {
      const int so = (((ks * 4 + l4) ^ swz) << 3);
      short8 av[4], bv[4];
#pragma unroll
      for (int i = 0; i < 4; ++i)
        av[i] = *(const short8*)&As[buf][(wr + i * 16 + l15) * 64 + so];
#pragma unroll
      for (int j = 0; j < 4; ++j)
        bv[j] = *(const short8*)&Bs[buf][(wc + j * 16 + l15) * 64 + so];
#pragma unroll
      for (int i = 0; i < 4; ++i)
#pragma unroll
        for (int j = 0; j < 4; ++j)
          acc[i][j] = __builtin_amdgcn_mfma_f32_16x16x32_bf16(av[i], bv[j],
                                                              acc[i][j], 0, 0, 0);
    }
  };

  stage(0, kbase);
  __syncthreads();
  for (int k0 = kbase; k0 < kbase + 1024; k0 += 128) {
    stage(1, k0 + 64);
    comp(0);
    __syncthreads();
    if (k0 + 128 < kbase + 1024) stage(0, k0 + 128);
    comp(1);
    __syncthreads();
  }

  u16* Pk = P + (size_t)kidx * BSZ * NPAD;
#pragma unroll
  for (int j = 0; j < 4; ++j) {
    const int col = bn0 + wc + j * 16 + l15;
#pragma unroll
    for (int i = 0; i < 4; ++i) {
#pragma unroll
      for (int r = 0; r < 4; ++r) {
        const int row = bm0 + wr + i * 16 + l4 * 4 + r;
        Pk[(size_t)row * NPAD + col] = f2bf(acc[i][j][r]);
      }
    }
  }
}

// ------ combine (fused f2): f2 = ||Fb[row]||^2 in-block, then
//        out = -0.1*sqrt(max(f2 + c2 - 2*(P0+P1), 0)). One block per row.
__global__ __launch_bounds__(256) void combine(const u16* __restrict__ Fb,
                                               const u16* __restrict__ P,
                                               const float* __restrict__ c2,
                                               float* __restrict__ out) {
  const int row = blockIdx.x;
  const int t = threadIdx.x;
  short8 v = *(const short8*)&Fb[(size_t)row * DTOT + t * 8];
  float s = 0.f;
#pragma unroll
  for (int q = 0; q < 8; ++q) { float f = bf2f((u16)v[q]); s += f * f; }
#pragma unroll
  for (int o = 32; o > 0; o >>= 1) s += __shfl_xor(s, o);
  __shared__ float red[4];
  if ((t & 63) == 0) red[t >> 6] = s;
  __syncthreads();
  const float fv = red[0] + red[1] + red[2] + red[3];

  const int c = t * 4;
  if (c >= NCLS) return;
  const short4v p0 = *(const short4v*)&P[(size_t)row * NPAD + c];
  const short4v p1 = *(const short4v*)&P[(size_t)(BSZ + row) * NPAD + c];
  const float4 cv = *(const float4*)&c2[c];
  float4 o;
  o.x = -0.1f * sqrtf(fmaxf(fv + cv.x - 2.f * (bf2f((u16)p0[0]) + bf2f((u16)p1[0])), 0.f));
  o.y = -0.1f * sqrtf(fmaxf(fv + cv.y - 2.f * (bf2f((u16)p0[1]) + bf2f((u16)p1[1])), 0.f));
  o.z = -0.1f * sqrtf(fmaxf(fv + cv.z - 2.f * (bf2f((u16)p0[2]) + bf2f((u16)p1[2])), 0.f));
  o.w = -0.1f * sqrtf(fmaxf(fv + cv.w - 2.f * (bf2f((u16)p0[3]) + bf2f((u16)p1[3])), 0.f));
  *(float4*)&out[(size_t)row * NCLS + c] = o;
}

extern "C" void kernel_launch(void* const* d_in, const int* in_sizes, int n_in,
                              void* d_out, int out_size, void* d_ws, size_t ws_size,
                              hipStream_t stream) {
  const float* x    = (const float*)d_in[0];
  const float* x90  = (const float*)d_in[1];
  const float* x180 = (const float*)d_in[2];
  const float* x270 = (const float*)d_in[3];
  const float* W_f  = (const float*)d_in[4];
  const float* b_f  = (const float*)d_in[5];
  const float* W_r  = (const float*)d_in[6];
  const float* b_r  = (const float*)d_in[7];
  const float* cen  = (const float*)d_in[8];
  float* out = (float*)d_out;

  u16* Wb = (u16*)d_ws;                         // [2][512][1024]
  u16* Cb = Wb + 2ull * FEAT * INF;             // [1024][2048]
  u16* Fb = Cb + (size_t)NPAD * DTOT;           // [4096][2048]
  u16* P  = Fb + (size_t)BSZ * DTOT;            // [2][4096][1024] bf16
  float* c2 = (float*)(P + 2ull * BSZ * NPAD);  // [1024]

  cvt_prep<<<1536, 256, 0, stream>>>(W_f, W_r, cen, Wb, Cb, c2);
  feat_gemm<<<512, 256, 0, stream>>>(x, x90, x180, x270, Wb, b_f, b_r, Fb);
  dist_gemm_sk<<<512, 256, 0, stream>>>(Fb, Cb, P);
  combine<<<BSZ, 256, 0, stream>>>(Fb, P, c2, out);
}